// Round 1
// baseline (1074.458 us; speedup 1.0000x reference)
//
#include <hip/hip_runtime.h>

#define LS 1323000
#define NB 98
#define MM 123000
#define BATCH 2
#define NROWS_T (NB*BATCH)
#define TWO_PI 6.28318530717958647692f

__device__ __forceinline__ float2 cmul(float2 a, float2 b){
  return make_float2(a.x*b.x - a.y*b.y, a.x*b.y + a.y*b.x);
}

// Small DFT of size R with sign S (+1 inverse, -1 forward), in-place on v[R].
template<int R,int S>
__device__ __forceinline__ void butterfly(float2* v){
  if constexpr (R==2){
    float2 a=v[0], b=v[1];
    v[0]=make_float2(a.x+b.x, a.y+b.y);
    v[1]=make_float2(a.x-b.x, a.y-b.y);
  } else if constexpr (R==4){
    float2 t0=make_float2(v[0].x+v[2].x, v[0].y+v[2].y);
    float2 t1=make_float2(v[0].x-v[2].x, v[0].y-v[2].y);
    float2 t2=make_float2(v[1].x+v[3].x, v[1].y+v[3].y);
    float2 t3=make_float2(v[1].x-v[3].x, v[1].y-v[3].y);
    v[0]=make_float2(t0.x+t2.x, t0.y+t2.y);
    v[2]=make_float2(t0.x-t2.x, t0.y-t2.y);
    // i*S*t3 = (-S*t3.y, S*t3.x)
    v[1]=make_float2(t1.x - (float)S*t3.y, t1.y + (float)S*t3.x);
    v[3]=make_float2(t1.x + (float)S*t3.y, t1.y - (float)S*t3.x);
  } else if constexpr (R==8){
    float2 e[4]={v[0],v[2],v[4],v[6]};
    float2 o[4]={v[1],v[3],v[5],v[7]};
    butterfly<4,S>(e);
    butterfly<4,S>(o);
    const float h = 0.70710678118654752440f;
    float2 w1=make_float2(h, (float)S*h);
    float2 w2=make_float2(0.f, (float)S);
    float2 w3=make_float2(-h, (float)S*h);
    float2 o1=cmul(o[1],w1), o2=cmul(o[2],w2), o3=cmul(o[3],w3);
    v[0]=make_float2(e[0].x+o[0].x, e[0].y+o[0].y);
    v[4]=make_float2(e[0].x-o[0].x, e[0].y-o[0].y);
    v[1]=make_float2(e[1].x+o1.x, e[1].y+o1.y);
    v[5]=make_float2(e[1].x-o1.x, e[1].y-o1.y);
    v[2]=make_float2(e[2].x+o2.x, e[2].y+o2.y);
    v[6]=make_float2(e[2].x-o2.x, e[2].y-o2.y);
    v[3]=make_float2(e[3].x+o3.x, e[3].y+o3.y);
    v[7]=make_float2(e[3].x-o3.x, e[3].y-o3.y);
  } else {
    // generic odd radix, direct DFT; all loops fully unrolled so sincos args
    // are compile-time constants.
    float2 x[R];
    #pragma unroll
    for(int k=0;k<R;k++){
      float2 acc=v[0];
      #pragma unroll
      for(int n=1;n<R;n++){
        const int p=(k*n)%R;
        float ang = (float)S * (TWO_PI/(float)R) * (float)p;
        float sn,cs; __sincosf(ang,&sn,&cs);
        acc.x += v[n].x*cs - v[n].y*sn;
        acc.y += v[n].x*sn + v[n].y*cs;
      }
      x[k]=acc;
    }
    #pragma unroll
    for(int k=0;k<R;k++) v[k]=x[k];
  }
}

// One Stockham autosort pass, radix R, sign S. nrows independent FFTs of
// length N, laid out contiguously. Out-of-place in -> out.
template<int R,int S>
__global__ void __launch_bounds__(256)
fft_pass(const float2* __restrict__ in, float2* __restrict__ out,
         int N, int Ns, int nrows){
  const int T = N / R;
  long long gid = (long long)blockIdx.x*blockDim.x + threadIdx.x;
  if (gid >= (long long)T*nrows) return;
  int row = (int)(gid / T);
  int j   = (int)(gid - (long long)row*T);
  const float2* x = in  + (size_t)row*N;
  float2*       y = out + (size_t)row*N;
  int t = j % Ns;
  float u = (float)t / (float)(Ns*R);
  float ang = (float)S * TWO_PI * u;
  float sn,cs; __sincosf(ang,&sn,&cs);
  float2 w1=make_float2(cs,sn);
  float2 wr=make_float2(1.f,0.f);
  float2 v[R];
  #pragma unroll
  for(int r=0;r<R;r++){
    float2 a = x[j + r*T];
    v[r] = cmul(a, wr);
    wr = cmul(wr, w1);
  }
  butterfly<R,S>(v);
  int d = (j/Ns)*(Ns*R) + t;
  #pragma unroll
  for(int r=0;r<R;r++) y[d + r*Ns] = v[r];
}

// Radix-41 Stockham pass with the 41x41 DFT matrix staged in LDS
// (broadcast reads: all lanes read the same W entry each step).
__global__ void __launch_bounds__(256)
fft_pass41(const float2* __restrict__ in, float2* __restrict__ out,
           int N, int Ns, int nrows, int S){
  __shared__ float2 W[41*41];
  for (int i=threadIdx.x; i<41*41; i+=blockDim.x){
    int k=i/41, n=i-41*k;
    int p=(k*n)%41;
    float ang = (float)S*(TWO_PI/41.f)*(float)p;
    float sn,cs; __sincosf(ang,&sn,&cs);
    W[i]=make_float2(cs,sn);
  }
  __syncthreads();
  const int T = N/41;
  long long gid = (long long)blockIdx.x*blockDim.x + threadIdx.x;
  if (gid >= (long long)T*nrows) return;
  int row=(int)(gid/T);
  int j  =(int)(gid - (long long)row*T);
  const float2* x = in  + (size_t)row*N;
  float2*       y = out + (size_t)row*N;
  int t = j % Ns;
  float u=(float)t/(float)(Ns*41);
  float ang=(float)S*TWO_PI*u;
  float sn,cs; __sincosf(ang,&sn,&cs);
  float2 w1=make_float2(cs,sn);
  float2 wr=make_float2(1.f,0.f);
  float2 v[41];
  #pragma unroll
  for(int r=0;r<41;r++){
    v[r]=cmul(x[j + r*T], wr);
    wr=cmul(wr,w1);
  }
  int d=(j/Ns)*(Ns*41)+t;
  #pragma unroll 1
  for(int k=0;k<41;k++){
    const float2* Wk = &W[k*41];
    float2 acc=v[0];
    #pragma unroll
    for(int n=1;n<41;n++){
      float2 w=Wk[n];
      acc.x += v[n].x*w.x - v[n].y*w.y;
      acc.y += v[n].x*w.y + v[n].y*w.x;
    }
    y[d + k*Ns] = acc;
  }
}

__global__ void __launch_bounds__(256)
cast_kernel(const float* __restrict__ s, float2* __restrict__ dst, int n){
  int i = blockIdx.x*blockDim.x + threadIdx.x;
  if (i < n) dst[i] = make_float2(s[i], 0.f);
}

// t[b,j,m] = ft[b, idx[j,m]] * gw[j,m] / MM   (ifft normalization folded in)
__global__ void __launch_bounds__(256)
gather_kernel(const float2* __restrict__ ft, const int* __restrict__ idx,
              const float* __restrict__ gw, float2* __restrict__ out){
  int e = blockIdx.x*blockDim.x + threadIdx.x;
  if (e >= BATCH*NB*MM) return;
  int b = e / (NB*MM);
  int r = e - b*(NB*MM);
  int id = idx[r];
  float g = gw[r] * (1.0f/(float)MM);
  float2 f = ft[(size_t)b*LS + id];
  out[e] = make_float2(f.x*g, f.y*g);
}

extern "C" void kernel_launch(void* const* d_in, const int* in_sizes, int n_in,
                              void* d_out, int out_size, void* d_ws, size_t ws_size,
                              hipStream_t stream){
  const float* s   = (const float*)d_in[0];
  const int*   idx = (const int*)d_in[1];
  const float* gw  = (const float*)d_in[2];
  float2* out = (float2*)d_out;
  char* ws = (char*)d_ws;

  // Forward scratch (2 rows x LS complex = 21.17 MB each); these overlap the
  // inverse scratch region, which is only written after ft is consumed.
  float2* bufA = (float2*)ws;
  float2* bufB = (float2*)(ws + 21168128);   // 256-aligned, >= 2*LS*8 bytes
  float2* tA   = (float2*)ws;                // inverse ping buffer

  // 1) cast real input to complex
  {
    int n = BATCH*LS;
    cast_kernel<<<(n+255)/256, 256, 0, stream>>>(s, bufA, n);
  }

  // 2) forward FFT: 9 Stockham passes, radices 8,7,7,5,5,5,3,3,3
  float2* cur = bufA; float2* nxt = bufB;
  int Ns = 1;
  #define FWD(R) do{                                                         \
    long long tot = (long long)(LS/(R))*BATCH;                               \
    int blks = (int)((tot + 255)/256);                                       \
    fft_pass<R,-1><<<blks,256,0,stream>>>(cur, nxt, LS, Ns, BATCH);          \
    Ns *= (R);                                                               \
    { float2* tmp=cur; cur=nxt; nxt=tmp; }                                   \
  }while(0)
  FWD(8); FWD(7); FWD(7); FWD(5); FWD(5); FWD(5); FWD(3); FWD(3); FWD(3);
  #undef FWD
  // 9 passes (odd) -> result in bufB == cur

  // 3) gather + window + 1/MM scale, into d_out (complex layout == output layout)
  {
    int tot = BATCH*NB*MM;
    gather_kernel<<<(tot+255)/256, 256, 0, stream>>>(cur, idx, gw, out);
  }

  // 4) inverse FFT over 196 rows of length MM: radices 41,8,5,5,5,3 (6 passes,
  //    out -> tA -> out -> ... -> out). Chunk rows by available ws.
  size_t row_bytes = (size_t)MM * sizeof(float2);
  int max_chunk = (int)(ws_size / row_bytes);
  if (max_chunk > NROWS_T) max_chunk = NROWS_T;
  if (max_chunk < 1) max_chunk = 1;

  for (int c0 = 0; c0 < NROWS_T; c0 += max_chunk){
    int cr = NROWS_T - c0; if (cr > max_chunk) cr = max_chunk;
    float2* ocur = out + (size_t)c0*MM;
    float2* icur = ocur;   // read
    float2* inxt = tA;     // write
    int Ns2 = 1;
    {
      long long tot = (long long)(MM/41)*cr;
      int blks = (int)((tot + 255)/256);
      fft_pass41<<<blks,256,0,stream>>>(icur, inxt, MM, Ns2, cr, 1);
      Ns2 *= 41;
      float2* tmp=icur; icur=inxt; inxt=tmp;
    }
    #define INV(R) do{                                                       \
      long long tot = (long long)(MM/(R))*cr;                                \
      int blks = (int)((tot + 255)/256);                                     \
      fft_pass<R,1><<<blks,256,0,stream>>>(icur, inxt, MM, Ns2, cr);         \
      Ns2 *= (R);                                                            \
      { float2* tmp=icur; icur=inxt; inxt=tmp; }                             \
    }while(0)
    INV(8); INV(5); INV(5); INV(5); INV(3);
    #undef INV
    // 6 passes total -> final result back in the out chunk
  }
}

// Round 2
// 931.847 us; speedup vs baseline: 1.1530x; 1.1530x over previous
//
#include <hip/hip_runtime.h>

#define LS 1323000
#define NB 98
#define MM 123000
#define N2 3000            // MM / 41
#define BATCH 2
#define NROWS_T (NB*BATCH)
#define TWO_PI 6.28318530717958647692f

__device__ __forceinline__ float2 cmul(float2 a, float2 b){
  return make_float2(a.x*b.x - a.y*b.y, a.x*b.y + a.y*b.x);
}

// Small DFT of size R with sign S (+1 inverse, -1 forward), in-place on v[R].
template<int R,int S>
__device__ __forceinline__ void butterfly(float2* v){
  if constexpr (R==2){
    float2 a=v[0], b=v[1];
    v[0]=make_float2(a.x+b.x, a.y+b.y);
    v[1]=make_float2(a.x-b.x, a.y-b.y);
  } else if constexpr (R==4){
    float2 t0=make_float2(v[0].x+v[2].x, v[0].y+v[2].y);
    float2 t1=make_float2(v[0].x-v[2].x, v[0].y-v[2].y);
    float2 t2=make_float2(v[1].x+v[3].x, v[1].y+v[3].y);
    float2 t3=make_float2(v[1].x-v[3].x, v[1].y-v[3].y);
    v[0]=make_float2(t0.x+t2.x, t0.y+t2.y);
    v[2]=make_float2(t0.x-t2.x, t0.y-t2.y);
    v[1]=make_float2(t1.x - (float)S*t3.y, t1.y + (float)S*t3.x);
    v[3]=make_float2(t1.x + (float)S*t3.y, t1.y - (float)S*t3.x);
  } else if constexpr (R==8){
    float2 e[4]={v[0],v[2],v[4],v[6]};
    float2 o[4]={v[1],v[3],v[5],v[7]};
    butterfly<4,S>(e);
    butterfly<4,S>(o);
    const float h = 0.70710678118654752440f;
    float2 w1=make_float2(h, (float)S*h);
    float2 w2=make_float2(0.f, (float)S);
    float2 w3=make_float2(-h, (float)S*h);
    float2 o1=cmul(o[1],w1), o2=cmul(o[2],w2), o3=cmul(o[3],w3);
    v[0]=make_float2(e[0].x+o[0].x, e[0].y+o[0].y);
    v[4]=make_float2(e[0].x-o[0].x, e[0].y-o[0].y);
    v[1]=make_float2(e[1].x+o1.x, e[1].y+o1.y);
    v[5]=make_float2(e[1].x-o1.x, e[1].y-o1.y);
    v[2]=make_float2(e[2].x+o2.x, e[2].y+o2.y);
    v[6]=make_float2(e[2].x-o2.x, e[2].y-o2.y);
    v[3]=make_float2(e[3].x+o3.x, e[3].y+o3.y);
    v[7]=make_float2(e[3].x-o3.x, e[3].y-o3.y);
  } else {
    float2 x[R];
    #pragma unroll
    for(int k=0;k<R;k++){
      float2 acc=v[0];
      #pragma unroll
      for(int n=1;n<R;n++){
        const int p=(k*n)%R;
        float ang = (float)S * (TWO_PI/(float)R) * (float)p;
        float sn,cs; __sincosf(ang,&sn,&cs);
        acc.x += v[n].x*cs - v[n].y*sn;
        acc.y += v[n].x*sn + v[n].y*cs;
      }
      x[k]=acc;
    }
    #pragma unroll
    for(int k=0;k<R;k++) v[k]=x[k];
  }
}

// One global Stockham pass (forward only now).
template<int R,int S>
__global__ void __launch_bounds__(256)
fft_pass(const float2* __restrict__ in, float2* __restrict__ out,
         int N, int Ns, int nrows){
  const int T = N / R;
  long long gid = (long long)blockIdx.x*blockDim.x + threadIdx.x;
  if (gid >= (long long)T*nrows) return;
  int row = (int)(gid / T);
  int j   = (int)(gid - (long long)row*T);
  const float2* x = in  + (size_t)row*N;
  float2*       y = out + (size_t)row*N;
  int t = j % Ns;
  float u = (float)t / (float)(Ns*R);
  float ang = (float)S * TWO_PI * u;
  float sn,cs; __sincosf(ang,&sn,&cs);
  float2 w1=make_float2(cs,sn);
  float2 wr=make_float2(1.f,0.f);
  float2 v[R];
  #pragma unroll
  for(int r=0;r<R;r++){
    float2 a = x[j + r*T];
    v[r] = cmul(a, wr);
    wr = cmul(wr, w1);
  }
  butterfly<R,S>(v);
  int d = (j/Ns)*(Ns*R) + t;
  #pragma unroll
  for(int r=0;r<R;r++) y[d + r*Ns] = v[r];
}

// First forward pass: radix-8, Ns=1 (no twiddles), reads real input directly.
__global__ void __launch_bounds__(256)
fft_r2c8(const float* __restrict__ s, float2* __restrict__ y){
  const int T = LS/8;
  long long gid = (long long)blockIdx.x*blockDim.x + threadIdx.x;
  if (gid >= (long long)T*BATCH) return;
  int row = (int)(gid / T);
  int j   = (int)(gid - (long long)row*T);
  const float* x = s + (size_t)row*LS;
  float2*      yr = y + (size_t)row*LS;
  float2 v[8];
  #pragma unroll
  for(int r=0;r<8;r++) v[r] = make_float2(x[j + r*T], 0.f);
  butterfly<8,-1>(v);
  int d = 8*j;
  #pragma unroll
  for(int r=0;r<8;r++) yr[d + r] = v[r];
}

// ---------------- Inverse: four-step, MM = 41 * 3000 ----------------
// INV1: A[row][k1][n2] = sum_{n1} t[row][n1*3000+n2] * e^{+2pi i n1 k1/41},
// with t = ft[b, idx[jrow,n]] * gw[jrow,n] / MM fused in (gather).
#define N2TILE 64
__global__ void __launch_bounds__(256)
inv1_gather41(const float2* __restrict__ ft, const int* __restrict__ idx,
              const float* __restrict__ gw, float2* __restrict__ A, int row0){
  __shared__ float2 xs[41][N2TILE];   // 21.0 KB
  __shared__ float2 WT[41][48];       // WT[n1][k1], padded to 48; 15.7 KB
  const int row  = row0 + blockIdx.y;
  const int jrow = row % NB;
  const int b    = row / NB;

  for (int i = threadIdx.x; i < 41*48; i += 256){
    int n1 = i/48, k1 = i - 48*n1;
    float2 w = make_float2(1.f, 0.f);
    if (k1 < 41){
      int p = (n1*k1) % 41;
      float ang = (float)p * (TWO_PI/41.0f);
      float sn, cs; __sincosf(ang, &sn, &cs);
      w = make_float2(cs, sn);
    }
    WT[n1][k1] = w;
  }

  const int n2base = blockIdx.x * N2TILE;
  const int*   idxr = idx + (size_t)jrow*MM;
  const float* gwr  = gw  + (size_t)jrow*MM;
  const float2* ftb = ft  + (size_t)b*LS;
  for (int e = threadIdx.x; e < 41*N2TILE; e += 256){
    int n1 = e / N2TILE, n2l = e - n1*N2TILE;
    int n2 = n2base + n2l;
    float2 val = make_float2(0.f, 0.f);
    if (n2 < N2){
      int n = n1*N2 + n2;
      int id = idxr[n];
      float g = gwr[n] * (1.0f/(float)MM);
      float2 f = ftb[id];
      val = make_float2(f.x*g, f.y*g);
    }
    xs[n1][n2l] = val;
  }
  __syncthreads();

  const int lane = threadIdx.x & 63;
  const int grp  = threadIdx.x >> 6;
  const int n2   = n2base + lane;
  float2* Arow = A + (size_t)blockIdx.y*MM;

  #pragma unroll
  for (int chunk = 0; chunk < 3; chunk++){
    const int k1c = chunk*16 + grp*4;
    float2 a0=make_float2(0,0), a1=a0, a2=a0, a3=a0;
    #pragma unroll 1
    for (int n1 = 0; n1 < 41; n1++){
      float2 x = xs[n1][lane];
      float4 w01 = *(const float4*)&WT[n1][k1c];
      float4 w23 = *(const float4*)&WT[n1][k1c+2];
      a0.x += x.x*w01.x - x.y*w01.y;  a0.y += x.x*w01.y + x.y*w01.x;
      a1.x += x.x*w01.z - x.y*w01.w;  a1.y += x.x*w01.w + x.y*w01.z;
      a2.x += x.x*w23.x - x.y*w23.y;  a2.y += x.x*w23.y + x.y*w23.x;
      a3.x += x.x*w23.z - x.y*w23.w;  a3.y += x.x*w23.w + x.y*w23.z;
    }
    if (n2 < N2){
      if (k1c+0 < 41) Arow[(size_t)(k1c+0)*N2 + n2] = a0;
      if (k1c+1 < 41) Arow[(size_t)(k1c+1)*N2 + n2] = a1;
      if (k1c+2 < 41) Arow[(size_t)(k1c+2)*N2 + n2] = a2;
      if (k1c+3 < 41) Arow[(size_t)(k1c+3)*N2 + n2] = a3;
    }
  }
}

// INV2: per (row,k1): load A[row][k1][:], twiddle e^{+2pi i n2 k1 / MM},
// 3000-point FFT in LDS (radices 5,5,5,3,8), write X[k2*41+k1].
template<int R, int Ns>
__device__ __forceinline__ void lds_stage(const float2* src, float2* dst, int tid){
  const int T = N2 / R;
  for (int j = tid; j < T; j += 256){
    int t = j % Ns;
    float2 w1;
    if constexpr (Ns == 1) w1 = make_float2(1.f, 0.f);
    else {
      float ang = TWO_PI * (float)t / (float)(Ns*R);
      float sn, cs; __sincosf(ang, &sn, &cs);
      w1 = make_float2(cs, sn);
    }
    float2 wr = make_float2(1.f, 0.f);
    float2 v[R];
    #pragma unroll
    for (int r = 0; r < R; r++){ v[r] = cmul(src[j + r*T], wr); wr = cmul(wr, w1); }
    butterfly<R,1>(v);
    int d = (j/Ns)*(Ns*R) + t;
    #pragma unroll
    for (int r = 0; r < R; r++) dst[d + r*Ns] = v[r];
  }
}

__global__ void __launch_bounds__(256)
inv2_fft3000(const float2* __restrict__ A, float2* __restrict__ out){
  __shared__ float2 u0[N2];  // 24 KB
  __shared__ float2 u1[N2];  // 24 KB
  const int k1 = blockIdx.x;
  const int tid = threadIdx.x;
  const float2* a = A + (size_t)blockIdx.y*MM + (size_t)k1*N2;
  float2* o = out + (size_t)blockIdx.y*MM;

  const float k1f = (float)k1 * (TWO_PI/(float)MM);
  for (int i = tid; i < N2; i += 256){
    float2 v = a[i];
    float ang = (float)(i*k1) * (TWO_PI/(float)MM);   // i*k1 <= 119960, exact in fp32
    float sn, cs; __sincosf(ang, &sn, &cs);
    u0[i] = cmul(v, make_float2(cs, sn));
  }
  (void)k1f;
  __syncthreads();
  lds_stage<5,1>(u0, u1, tid);   __syncthreads();
  lds_stage<5,5>(u1, u0, tid);   __syncthreads();
  lds_stage<5,25>(u0, u1, tid);  __syncthreads();
  lds_stage<3,125>(u1, u0, tid); __syncthreads();
  lds_stage<8,375>(u0, u1, tid); __syncthreads();
  for (int p = tid; p < N2; p += 256)
    o[(size_t)p*41 + k1] = u1[p];
}

extern "C" void kernel_launch(void* const* d_in, const int* in_sizes, int n_in,
                              void* d_out, int out_size, void* d_ws, size_t ws_size,
                              hipStream_t stream){
  const float* s   = (const float*)d_in[0];
  const int*   idx = (const int*)d_in[1];
  const float* gw  = (const float*)d_in[2];
  float2* out = (float2*)d_out;
  char* ws = (char*)d_ws;

  const size_t FWD_BYTES = 21168128;            // >= BATCH*LS*8, 256-aligned
  float2* bufA = (float2*)ws;
  float2* bufB = (float2*)(ws + FWD_BYTES);

  // 1) forward FFT: radix-8 (r2c, no twiddle) + 8 Stockham passes 7,7,5,5,5,3,3,3
  {
    long long tot = (long long)(LS/8)*BATCH;
    int blks = (int)((tot + 255)/256);
    fft_r2c8<<<blks,256,0,stream>>>(s, bufA);
  }
  float2* cur = bufA; float2* nxt = bufB;
  int Ns = 8;
  #define FWD(R) do{                                                         \
    long long tot = (long long)(LS/(R))*BATCH;                               \
    int blks = (int)((tot + 255)/256);                                       \
    fft_pass<R,-1><<<blks,256,0,stream>>>(cur, nxt, LS, Ns, BATCH);          \
    Ns *= (R);                                                               \
    { float2* tmp=cur; cur=nxt; nxt=tmp; }                                   \
  }while(0)
  FWD(7); FWD(7); FWD(5); FWD(5); FWD(5); FWD(3); FWD(3); FWD(3);
  #undef FWD
  // 8 swaps -> ft is back in bufA == cur

  // 2) inverse four-step, chunked over rows by available workspace.
  float2* Abase = (float2*)(ws + 2*FWD_BYTES);
  size_t row_bytes = (size_t)MM * sizeof(float2);
  size_t avail = (ws_size > 2*FWD_BYTES) ? (ws_size - 2*FWD_BYTES) : 0;
  int max_chunk = (int)(avail / row_bytes);
  if (max_chunk > NROWS_T) max_chunk = NROWS_T;
  if (max_chunk < 1) max_chunk = 1;

  const int n2tiles = (N2 + N2TILE - 1)/N2TILE;   // 47
  for (int c0 = 0; c0 < NROWS_T; c0 += max_chunk){
    int cr = NROWS_T - c0; if (cr > max_chunk) cr = max_chunk;
    dim3 g1(n2tiles, cr);
    inv1_gather41<<<g1,256,0,stream>>>(cur, idx, gw, Abase, c0);
    dim3 g2(41, cr);
    inv2_fft3000<<<g2,256,0,stream>>>(Abase, out + (size_t)c0*MM);
  }
}

// Round 3
// 868.366 us; speedup vs baseline: 1.2373x; 1.0731x over previous
//
#include <hip/hip_runtime.h>

#define LS 1323000
#define NB 98
#define MM 123000
#define N2 3000            // MM / 41
#define BATCH 2
#define NROWS_T (NB*BATCH)
#define TWO_PI 6.28318530717958647692f

__device__ __forceinline__ float2 cmul(float2 a, float2 b){
  return make_float2(a.x*b.x - a.y*b.y, a.x*b.y + a.y*b.x);
}

// Small DFT of size R with sign S (+1 inverse, -1 forward), in-place on v[R].
template<int R,int S>
__device__ __forceinline__ void butterfly(float2* v){
  if constexpr (R==2){
    float2 a=v[0], b=v[1];
    v[0]=make_float2(a.x+b.x, a.y+b.y);
    v[1]=make_float2(a.x-b.x, a.y-b.y);
  } else if constexpr (R==4){
    float2 t0=make_float2(v[0].x+v[2].x, v[0].y+v[2].y);
    float2 t1=make_float2(v[0].x-v[2].x, v[0].y-v[2].y);
    float2 t2=make_float2(v[1].x+v[3].x, v[1].y+v[3].y);
    float2 t3=make_float2(v[1].x-v[3].x, v[1].y-v[3].y);
    v[0]=make_float2(t0.x+t2.x, t0.y+t2.y);
    v[2]=make_float2(t0.x-t2.x, t0.y-t2.y);
    v[1]=make_float2(t1.x - (float)S*t3.y, t1.y + (float)S*t3.x);
    v[3]=make_float2(t1.x + (float)S*t3.y, t1.y - (float)S*t3.x);
  } else if constexpr (R==8){
    float2 e[4]={v[0],v[2],v[4],v[6]};
    float2 o[4]={v[1],v[3],v[5],v[7]};
    butterfly<4,S>(e);
    butterfly<4,S>(o);
    const float h = 0.70710678118654752440f;
    float2 w1=make_float2(h, (float)S*h);
    float2 w2=make_float2(0.f, (float)S);
    float2 w3=make_float2(-h, (float)S*h);
    float2 o1=cmul(o[1],w1), o2=cmul(o[2],w2), o3=cmul(o[3],w3);
    v[0]=make_float2(e[0].x+o[0].x, e[0].y+o[0].y);
    v[4]=make_float2(e[0].x-o[0].x, e[0].y-o[0].y);
    v[1]=make_float2(e[1].x+o1.x, e[1].y+o1.y);
    v[5]=make_float2(e[1].x-o1.x, e[1].y-o1.y);
    v[2]=make_float2(e[2].x+o2.x, e[2].y+o2.y);
    v[6]=make_float2(e[2].x-o2.x, e[2].y-o2.y);
    v[3]=make_float2(e[3].x+o3.x, e[3].y+o3.y);
    v[7]=make_float2(e[3].x-o3.x, e[3].y-o3.y);
  } else {
    float2 x[R];
    #pragma unroll
    for(int k=0;k<R;k++){
      float2 acc=v[0];
      #pragma unroll
      for(int n=1;n<R;n++){
        const int p=(k*n)%R;
        float ang = (float)S * (TWO_PI/(float)R) * (float)p;
        float sn,cs; __sincosf(ang,&sn,&cs);
        acc.x += v[n].x*cs - v[n].y*sn;
        acc.y += v[n].x*sn + v[n].y*cs;
      }
      x[k]=acc;
    }
    #pragma unroll
    for(int k=0;k<R;k++) v[k]=x[k];
  }
}

// One global Stockham pass (forward only).
template<int R,int S>
__global__ void __launch_bounds__(256)
fft_pass(const float2* __restrict__ in, float2* __restrict__ out,
         int N, int Ns, int nrows){
  const int T = N / R;
  long long gid = (long long)blockIdx.x*blockDim.x + threadIdx.x;
  if (gid >= (long long)T*nrows) return;
  int row = (int)(gid / T);
  int j   = (int)(gid - (long long)row*T);
  const float2* x = in  + (size_t)row*N;
  float2*       y = out + (size_t)row*N;
  int t = j % Ns;
  float u = (float)t / (float)(Ns*R);
  float ang = (float)S * TWO_PI * u;
  float sn,cs; __sincosf(ang,&sn,&cs);
  float2 w1=make_float2(cs,sn);
  float2 wr=make_float2(1.f,0.f);
  float2 v[R];
  #pragma unroll
  for(int r=0;r<R;r++){
    float2 a = x[j + r*T];
    v[r] = cmul(a, wr);
    wr = cmul(wr, w1);
  }
  butterfly<R,S>(v);
  int d = (j/Ns)*(Ns*R) + t;
  #pragma unroll
  for(int r=0;r<R;r++) y[d + r*Ns] = v[r];
}

// First forward pass: radix-8, Ns=1 (no twiddles), reads real input directly.
__global__ void __launch_bounds__(256)
fft_r2c8(const float* __restrict__ s, float2* __restrict__ y){
  const int T = LS/8;
  long long gid = (long long)blockIdx.x*blockDim.x + threadIdx.x;
  if (gid >= (long long)T*BATCH) return;
  int row = (int)(gid / T);
  int j   = (int)(gid - (long long)row*T);
  const float* x = s + (size_t)row*LS;
  float2*      yr = y + (size_t)row*LS;
  float2 v[8];
  #pragma unroll
  for(int r=0;r<8;r++) v[r] = make_float2(x[j + r*T], 0.f);
  butterfly<8,-1>(v);
  int d = 8*j;
  #pragma unroll
  for(int r=0;r<8;r++) yr[d + r] = v[r];
}

// Per-row nonzero extents of gw: head [0, A), tail [B, MM). h1<=61500<=Mmax-h2
// always, so splitting the scan at 61500 is safe; missing zero-valued window
// endpoints is exact (they contribute nothing).
__global__ void __launch_bounds__(256)
rowspan_kernel(const float* __restrict__ gw, int2* __restrict__ span){
  __shared__ int sA[256], sB[256];
  const int j = blockIdx.x, tid = threadIdx.x;
  const float* g = gw + (size_t)j*MM;
  int mA = -1, mB = MM;
  for (int m = tid; m < 61500; m += 256) if (g[m] != 0.f && m > mA) mA = m;
  for (int m = 61500 + tid; m < MM; m += 256) if (g[m] != 0.f && m < mB) mB = m;
  sA[tid]=mA; sB[tid]=mB; __syncthreads();
  for (int s=128; s>0; s>>=1){
    if (tid<s){ sA[tid]=max(sA[tid],sA[tid+s]); sB[tid]=min(sB[tid],sB[tid+s]); }
    __syncthreads();
  }
  if (tid==0) span[j] = make_int2(sA[0]+1, sB[0]);
}

// LDS Stockham stage for the 3000-pt inverse FFT.
template<int R, int Ns>
__device__ __forceinline__ void lds_stage(const float2* src, float2* dst, int tid){
  const int T = N2 / R;
  for (int j = tid; j < T; j += 256){
    int t = j % Ns;
    float2 w1;
    if constexpr (Ns == 1) w1 = make_float2(1.f, 0.f);
    else {
      float ang = TWO_PI * (float)t / (float)(Ns*R);
      float sn, cs; __sincosf(ang, &sn, &cs);
      w1 = make_float2(cs, sn);
    }
    float2 wr = make_float2(1.f, 0.f);
    float2 v[R];
    #pragma unroll
    for (int r = 0; r < R; r++){ v[r] = cmul(src[j + r*T], wr); wr = cmul(wr, w1); }
    butterfly<R,1>(v);
    int d = (j/Ns)*(Ns*R) + t;
    #pragma unroll
    for (int r = 0; r < R; r++) dst[d + r*Ns] = v[r];
  }
}

// Inverse stage 1. Decomposition n = n2 + 41*n1, k = k1 + 3000*k2:
// B[n2][k1] = e^{2pi i n2 k1/MM} * sum_{n1} t[n2+41*n1] e^{2pi i n1 k1/3000},
// t fused from gather (idx/gw/ft), span-pruned, 1/MM folded in.
__global__ void __launch_bounds__(256)
inv_s1(const float2* __restrict__ ft, const int* __restrict__ idx,
       const float* __restrict__ gw, const int2* __restrict__ span,
       float2* __restrict__ Bb, int row0){
  __shared__ float2 u0[N2];  // 24 KB
  __shared__ float2 u1[N2];  // 24 KB
  const int n2  = blockIdx.x;            // 0..40
  const int row = row0 + blockIdx.y;
  const int jrow = row % NB;
  const int b    = row / NB;
  const int tid = threadIdx.x;
  const int2 sp = span[jrow];
  // n = n2 + 41*i nonzero only for i < n1A or i >= n1B
  const int n1A = (sp.x - n2 + 40) / 41;
  const int n1B = (sp.y - n2 + 40) / 41;
  const int*   idxr = idx + (size_t)jrow*MM;
  const float* gwr  = gw  + (size_t)jrow*MM;
  const float2* ftb = ft  + (size_t)b*LS;
  for (int i = tid; i < N2; i += 256){
    float2 val = make_float2(0.f, 0.f);
    if (i < n1A || i >= n1B){
      int n = n2 + 41*i;
      int id = idxr[n];
      float g = gwr[n] * (1.0f/(float)MM);
      float2 f = ftb[id];
      val = make_float2(f.x*g, f.y*g);
    }
    u0[i] = val;
  }
  __syncthreads();
  lds_stage<5,1>(u0, u1, tid);   __syncthreads();
  lds_stage<5,5>(u1, u0, tid);   __syncthreads();
  lds_stage<5,25>(u0, u1, tid);  __syncthreads();
  lds_stage<3,125>(u1, u0, tid); __syncthreads();
  lds_stage<8,375>(u0, u1, tid); __syncthreads();
  float2* Brow = Bb + (size_t)blockIdx.y*MM + (size_t)n2*N2;
  for (int k1 = tid; k1 < N2; k1 += 256){
    float ang = (float)(n2*k1) * (TWO_PI/(float)MM);  // n2*k1 <= 119960, exact fp32
    float sn, cs; __sincosf(ang, &sn, &cs);
    Brow[k1] = cmul(u1[k1], make_float2(cs, sn));
  }
}

// Inverse stage 2: X[k1 + 3000*k2] = sum_{n2<41} B[n2][k1] e^{2pi i n2 k2/41}.
// Loads and stores both coalesced (contiguous in k1 for fixed k2).
#define K1TILE 64
__global__ void __launch_bounds__(256)
inv_s2(const float2* __restrict__ Bb, float2* __restrict__ out, int row0){
  __shared__ float2 xs[41][K1TILE];   // 21 KB
  __shared__ float2 W[41][48];        // 15.4 KB, [n2][k2] padded
  const int tid = threadIdx.x;
  for (int i = tid; i < 41*48; i += 256){
    int n2 = i/48, k2 = i - 48*n2;
    float2 w = make_float2(1.f, 0.f);
    if (k2 < 41){
      int p = (n2*k2) % 41;
      float ang = (float)p * (TWO_PI/41.f);
      float sn, cs; __sincosf(ang, &sn, &cs);
      w = make_float2(cs, sn);
    }
    W[n2][k2] = w;
  }
  const int k1base = blockIdx.x * K1TILE;
  const float2* Brow = Bb + (size_t)blockIdx.y*MM;
  for (int e = tid; e < 41*K1TILE; e += 256){
    int n2 = e / K1TILE, l = e - n2*K1TILE;
    int k1 = k1base + l;
    xs[n2][l] = (k1 < N2) ? Brow[(size_t)n2*N2 + k1] : make_float2(0.f, 0.f);
  }
  __syncthreads();
  const int lane = tid & 63, grp = tid >> 6;
  const int k1 = k1base + lane;
  float2* orow = out + (size_t)blockIdx.y*MM;
  (void)row0;
  #pragma unroll
  for (int c = 0; c < 3; c++){
    const int k2c = c*16 + grp*4;
    float2 a0=make_float2(0,0), a1=a0, a2=a0, a3=a0;
    #pragma unroll 1
    for (int n2 = 0; n2 < 41; n2++){
      float2 x = xs[n2][lane];
      float4 w01 = *(const float4*)&W[n2][k2c];
      float4 w23 = *(const float4*)&W[n2][k2c+2];
      a0.x += x.x*w01.x - x.y*w01.y;  a0.y += x.x*w01.y + x.y*w01.x;
      a1.x += x.x*w01.z - x.y*w01.w;  a1.y += x.x*w01.w + x.y*w01.z;
      a2.x += x.x*w23.x - x.y*w23.y;  a2.y += x.x*w23.y + x.y*w23.x;
      a3.x += x.x*w23.z - x.y*w23.w;  a3.y += x.x*w23.w + x.y*w23.z;
    }
    if (k1 < N2){
      if (k2c+0 < 41) orow[(size_t)(k2c+0)*N2 + k1] = a0;
      if (k2c+1 < 41) orow[(size_t)(k2c+1)*N2 + k1] = a1;
      if (k2c+2 < 41) orow[(size_t)(k2c+2)*N2 + k1] = a2;
      if (k2c+3 < 41) orow[(size_t)(k2c+3)*N2 + k1] = a3;
    }
  }
}

extern "C" void kernel_launch(void* const* d_in, const int* in_sizes, int n_in,
                              void* d_out, int out_size, void* d_ws, size_t ws_size,
                              hipStream_t stream){
  const float* s   = (const float*)d_in[0];
  const int*   idx = (const int*)d_in[1];
  const float* gw  = (const float*)d_in[2];
  float2* out = (float2*)d_out;
  char* ws = (char*)d_ws;

  const size_t FWD_BYTES = 21168128;            // >= BATCH*LS*8, 256-aligned
  float2* bufA = (float2*)ws;
  float2* bufB = (float2*)(ws + FWD_BYTES);
  int2*   span = (int2*)(ws + 2*FWD_BYTES);
  float2* Bbase = (float2*)(ws + 2*FWD_BYTES + 1024);

  // 1) forward FFT: radix-8 r2c + 8 Stockham passes 7,7,5,5,5,3,3,3
  {
    long long tot = (long long)(LS/8)*BATCH;
    int blks = (int)((tot + 255)/256);
    fft_r2c8<<<blks,256,0,stream>>>(s, bufA);
  }
  float2* cur = bufA; float2* nxt = bufB;
  int Ns = 8;
  #define FWD(R) do{                                                         \
    long long tot = (long long)(LS/(R))*BATCH;                               \
    int blks = (int)((tot + 255)/256);                                       \
    fft_pass<R,-1><<<blks,256,0,stream>>>(cur, nxt, LS, Ns, BATCH);          \
    Ns *= (R);                                                               \
    { float2* tmp=cur; cur=nxt; nxt=tmp; }                                   \
  }while(0)
  FWD(7); FWD(7); FWD(5); FWD(5); FWD(5); FWD(3); FWD(3); FWD(3);
  #undef FWD
  // 8 swaps -> ft back in bufA == cur

  // 2) per-row nonzero spans of gw
  rowspan_kernel<<<NB,256,0,stream>>>(gw, span);

  // 3) inverse four-step, chunked by workspace
  size_t row_bytes = (size_t)MM * sizeof(float2);
  size_t used = 2*FWD_BYTES + 1024;
  size_t avail = (ws_size > used) ? (ws_size - used) : 0;
  int max_chunk = (int)(avail / row_bytes);
  if (max_chunk > NROWS_T) max_chunk = NROWS_T;
  if (max_chunk < 1) max_chunk = 1;

  const int k1tiles = (N2 + K1TILE - 1)/K1TILE;   // 47
  for (int c0 = 0; c0 < NROWS_T; c0 += max_chunk){
    int cr = NROWS_T - c0; if (cr > max_chunk) cr = max_chunk;
    dim3 g1(41, cr);
    inv_s1<<<g1,256,0,stream>>>(cur, idx, gw, span, Bbase, c0);
    dim3 g2(k1tiles, cr);
    inv_s2<<<g2,256,0,stream>>>(Bbase, out + (size_t)c0*MM, c0);
  }
}

// Round 4
// 715.648 us; speedup vs baseline: 1.5014x; 1.2134x over previous
//
#include <hip/hip_runtime.h>

#define LS 1323000
#define NB 98
#define MM 123000
#define N2 3000            // MM / 41
#define BATCH 2
#define NROWS_T (NB*BATCH)
#define TWO_PI 6.28318530717958647692f

// Bb bf16 layout per row: [kb<188][q<96][kl<16], ushort units
#define KBN 188
#define QN  96
#define SROW (KBN*QN*16)       // 288768 ushorts = 577536 B per row
#define QP  104                // padded q stride in LDS (bank-conflict-free)

typedef __attribute__((ext_vector_type(8))) short short8;
typedef __attribute__((ext_vector_type(4))) float f32x4;

__device__ __forceinline__ float2 cmul(float2 a, float2 b){
  return make_float2(a.x*b.x - a.y*b.y, a.x*b.y + a.y*b.x);
}
__device__ __forceinline__ unsigned short f2bf(float f){
  unsigned int u = __float_as_uint(f);
  unsigned int r = (u + 0x7FFFu + ((u >> 16) & 1u)) >> 16;
  return (unsigned short)r;
}

// Small DFT of size R with sign S (+1 inverse, -1 forward), in-place on v[R].
template<int R,int S>
__device__ __forceinline__ void butterfly(float2* v){
  if constexpr (R==2){
    float2 a=v[0], b=v[1];
    v[0]=make_float2(a.x+b.x, a.y+b.y);
    v[1]=make_float2(a.x-b.x, a.y-b.y);
  } else if constexpr (R==4){
    float2 t0=make_float2(v[0].x+v[2].x, v[0].y+v[2].y);
    float2 t1=make_float2(v[0].x-v[2].x, v[0].y-v[2].y);
    float2 t2=make_float2(v[1].x+v[3].x, v[1].y+v[3].y);
    float2 t3=make_float2(v[1].x-v[3].x, v[1].y-v[3].y);
    v[0]=make_float2(t0.x+t2.x, t0.y+t2.y);
    v[2]=make_float2(t0.x-t2.x, t0.y-t2.y);
    v[1]=make_float2(t1.x - (float)S*t3.y, t1.y + (float)S*t3.x);
    v[3]=make_float2(t1.x + (float)S*t3.y, t1.y - (float)S*t3.x);
  } else if constexpr (R==8){
    float2 e[4]={v[0],v[2],v[4],v[6]};
    float2 o[4]={v[1],v[3],v[5],v[7]};
    butterfly<4,S>(e);
    butterfly<4,S>(o);
    const float h = 0.70710678118654752440f;
    float2 w1=make_float2(h, (float)S*h);
    float2 w2=make_float2(0.f, (float)S);
    float2 w3=make_float2(-h, (float)S*h);
    float2 o1=cmul(o[1],w1), o2=cmul(o[2],w2), o3=cmul(o[3],w3);
    v[0]=make_float2(e[0].x+o[0].x, e[0].y+o[0].y);
    v[4]=make_float2(e[0].x-o[0].x, e[0].y-o[0].y);
    v[1]=make_float2(e[1].x+o1.x, e[1].y+o1.y);
    v[5]=make_float2(e[1].x-o1.x, e[1].y-o1.y);
    v[2]=make_float2(e[2].x+o2.x, e[2].y+o2.y);
    v[6]=make_float2(e[2].x-o2.x, e[2].y-o2.y);
    v[3]=make_float2(e[3].x+o3.x, e[3].y+o3.y);
    v[7]=make_float2(e[3].x-o3.x, e[3].y-o3.y);
  } else {
    float2 x[R];
    #pragma unroll
    for(int k=0;k<R;k++){
      float2 acc=v[0];
      #pragma unroll
      for(int n=1;n<R;n++){
        const int p=(k*n)%R;
        float ang = (float)S * (TWO_PI/(float)R) * (float)p;
        float sn,cs; __sincosf(ang,&sn,&cs);
        acc.x += v[n].x*cs - v[n].y*sn;
        acc.y += v[n].x*sn + v[n].y*cs;
      }
      x[k]=acc;
    }
    #pragma unroll
    for(int k=0;k<R;k++) v[k]=x[k];
  }
}

// One global Stockham pass (forward only).
template<int R,int S>
__global__ void __launch_bounds__(256)
fft_pass(const float2* __restrict__ in, float2* __restrict__ out,
         int N, int Ns, int nrows){
  const int T = N / R;
  long long gid = (long long)blockIdx.x*blockDim.x + threadIdx.x;
  if (gid >= (long long)T*nrows) return;
  int row = (int)(gid / T);
  int j   = (int)(gid - (long long)row*T);
  const float2* x = in  + (size_t)row*N;
  float2*       y = out + (size_t)row*N;
  int t = j % Ns;
  float u = (float)t / (float)(Ns*R);
  float ang = (float)S * TWO_PI * u;
  float sn,cs; __sincosf(ang,&sn,&cs);
  float2 w1=make_float2(cs,sn);
  float2 wr=make_float2(1.f,0.f);
  float2 v[R];
  #pragma unroll
  for(int r=0;r<R;r++){
    float2 a = x[j + r*T];
    v[r] = cmul(a, wr);
    wr = cmul(wr, w1);
  }
  butterfly<R,S>(v);
  int d = (j/Ns)*(Ns*R) + t;
  #pragma unroll
  for(int r=0;r<R;r++) y[d + r*Ns] = v[r];
}

// First forward pass: radix-8, Ns=1 (no twiddles), reads real input directly.
__global__ void __launch_bounds__(256)
fft_r2c8(const float* __restrict__ s, float2* __restrict__ y){
  const int T = LS/8;
  long long gid = (long long)blockIdx.x*blockDim.x + threadIdx.x;
  if (gid >= (long long)T*BATCH) return;
  int row = (int)(gid / T);
  int j   = (int)(gid - (long long)row*T);
  const float* x = s + (size_t)row*LS;
  float2*      yr = y + (size_t)row*LS;
  float2 v[8];
  #pragma unroll
  for(int r=0;r<8;r++) v[r] = make_float2(x[j + r*T], 0.f);
  butterfly<8,-1>(v);
  int d = 8*j;
  #pragma unroll
  for(int r=0;r<8;r++) yr[d + r] = v[r];
}

// Per-row nonzero extents of gw: head [0, A), tail [B, MM).
__global__ void __launch_bounds__(256)
rowspan_kernel(const float* __restrict__ gw, int2* __restrict__ span){
  __shared__ int sA[256], sB[256];
  const int j = blockIdx.x, tid = threadIdx.x;
  const float* g = gw + (size_t)j*MM;
  int mA = -1, mB = MM;
  for (int m = tid; m < 61500; m += 256) if (g[m] != 0.f && m > mA) mA = m;
  for (int m = 61500 + tid; m < MM; m += 256) if (g[m] != 0.f && m < mB) mB = m;
  sA[tid]=mA; sB[tid]=mB; __syncthreads();
  for (int s=128; s>0; s>>=1){
    if (tid<s){ sA[tid]=max(sA[tid],sA[tid+s]); sB[tid]=min(sB[tid],sB[tid+s]); }
    __syncthreads();
  }
  if (tid==0) span[j] = make_int2(sA[0]+1, sB[0]);
}

// Precompute the 96x96 (padded to [96][QP]) bf16 real-form W matrix:
// A[2k2+c][2n2+c']: c=0: (Wr, -Wi), c=1: (Wi, Wr), W = e^{2pi i n2 k2/41}.
__global__ void __launch_bounds__(256)
a_prep(unsigned short* __restrict__ A96){
  int i = blockIdx.x*blockDim.x + threadIdx.x;
  if (i >= 96*QP) return;
  int R = i / QP, q = i - R*QP;
  float val = 0.f;
  if (R < 82 && q < 82){
    int k2 = R >> 1, c = R & 1, n2 = q >> 1, cp = q & 1;
    int p = (k2*n2) % 41;
    float ang = (float)p * (TWO_PI/41.f);
    float sn, cs; __sincosf(ang, &sn, &cs);
    val = c ? (cp ? cs : sn) : (cp ? -sn : cs);
  }
  A96[i] = f2bf(val);
}

// LDS Stockham stage for the 3000-pt inverse FFT.
template<int R, int Ns>
__device__ __forceinline__ void lds_stage(const float2* src, float2* dst, int tid){
  const int T = N2 / R;
  for (int j = tid; j < T; j += 256){
    int t = j % Ns;
    float2 w1;
    if constexpr (Ns == 1) w1 = make_float2(1.f, 0.f);
    else {
      float ang = TWO_PI * (float)t / (float)(Ns*R);
      float sn, cs; __sincosf(ang, &sn, &cs);
      w1 = make_float2(cs, sn);
    }
    float2 wr = make_float2(1.f, 0.f);
    float2 v[R];
    #pragma unroll
    for (int r = 0; r < R; r++){ v[r] = cmul(src[j + r*T], wr); wr = cmul(wr, w1); }
    butterfly<R,1>(v);
    int d = (j/Ns)*(Ns*R) + t;
    #pragma unroll
    for (int r = 0; r < R; r++) dst[d + r*Ns] = v[r];
  }
}

// Inverse stage 1: per (row, n2): span-pruned gather -> 3000-pt LDS FFT ->
// twiddle -> bf16 store into MFMA-tiled layout [kb][q=2n2+comp][kl].
__global__ void __launch_bounds__(256)
inv_s1(const float2* __restrict__ ft, const int* __restrict__ idx,
       const float* __restrict__ gw, const int2* __restrict__ span,
       unsigned short* __restrict__ Bb, int row0){
  __shared__ float2 u0[N2];  // 24 KB
  __shared__ float2 u1[N2];  // 24 KB
  const int n2  = blockIdx.x;            // 0..40
  const int row = row0 + blockIdx.y;
  const int jrow = row % NB;
  const int b    = row / NB;
  const int tid = threadIdx.x;
  const int2 sp = span[jrow];
  const int n1A = (sp.x - n2 + 40) / 41;
  const int n1B = (sp.y - n2 + 40) / 41;
  const int*   idxr = idx + (size_t)jrow*MM;
  const float* gwr  = gw  + (size_t)jrow*MM;
  const float2* ftb = ft  + (size_t)b*LS;
  for (int i = tid; i < N2; i += 256){
    float2 val = make_float2(0.f, 0.f);
    if (i < n1A || i >= n1B){
      int n = n2 + 41*i;
      int id = idxr[n];
      float g = gwr[n] * (1.0f/(float)MM);
      float2 f = ftb[id];
      val = make_float2(f.x*g, f.y*g);
    }
    u0[i] = val;
  }
  __syncthreads();
  lds_stage<5,1>(u0, u1, tid);   __syncthreads();
  lds_stage<5,5>(u1, u0, tid);   __syncthreads();
  lds_stage<5,25>(u0, u1, tid);  __syncthreads();
  lds_stage<3,125>(u1, u0, tid); __syncthreads();
  lds_stage<8,375>(u0, u1, tid); __syncthreads();
  unsigned short* Brow = Bb + (size_t)blockIdx.y*SROW;
  const int qr = 2*n2, qi = 2*n2+1;
  for (int k1 = tid; k1 < N2; k1 += 256){
    float ang = (float)(n2*k1) * (TWO_PI/(float)MM);  // n2*k1 <= 119960, exact fp32
    float sn, cs; __sincosf(ang, &sn, &cs);
    float2 v = cmul(u1[k1], make_float2(cs, sn));
    int kb = k1 >> 4, kl = k1 & 15;
    size_t base = (size_t)kb*(QN*16) + kl;
    Brow[base + qr*16] = f2bf(v.x);
    Brow[base + qi*16] = f2bf(v.y);
  }
}

// Inverse stage 2 via MFMA: Out[R][k1] = sum_q A96[R][q] * B[q][k1], bf16 in,
// fp32 out. Per block: 64 k1, all 96 R. 4 waves x (6 M-tiles x 3 K-steps).
__global__ void __launch_bounds__(256)
inv_s2_mfma(const unsigned short* __restrict__ A96,
            const unsigned short* __restrict__ Bb,
            float2* __restrict__ out){
  __shared__ unsigned short Als[96*QP];   // 19968 B
  __shared__ unsigned short Bls[64*QP];   // 13312 B
  const int tid = threadIdx.x;

  // stage A (straight copy; hot in L2)
  {
    const uint4* src = (const uint4*)A96;
    uint4* dst = (uint4*)Als;
    for (int f = tid; f < (96*QP*2)/16; f += 256) dst[f] = src[f];
  }
  // stage B tile [4 kb][96 q][16 kl] -> LDS transposed [k1l][q]
  {
    const unsigned short* Bt = Bb + (size_t)blockIdx.y*SROW
                                  + (size_t)blockIdx.x*4*(QN*16);
    for (int f = tid; f < 768; f += 256){
      uint4 d = *(const uint4*)(Bt + (size_t)f*8);
      int q   = (f >> 1) % QN;
      int kb  = f / (QN*2);
      int kl0 = (f & 1) * 8;
      if (q >= 82) d = make_uint4(0u,0u,0u,0u);
      const unsigned short* e = (const unsigned short*)&d;
      int rbase = kb*16 + kl0;
      #pragma unroll
      for (int j = 0; j < 8; j++)
        Bls[(rbase + j)*QP + q] = e[j];
    }
  }
  __syncthreads();

  const int w = tid >> 6, l = tid & 63;
  const int g = l >> 4, c = l & 15;

  f32x4 acc[6];
  #pragma unroll
  for (int m = 0; m < 6; m++) acc[m] = (f32x4){0.f,0.f,0.f,0.f};

  short8 b0 = *(const short8*)&Bls[(16*w + c)*QP +  0 + 8*g];
  short8 b1 = *(const short8*)&Bls[(16*w + c)*QP + 32 + 8*g];
  short8 b2 = *(const short8*)&Bls[(16*w + c)*QP + 64 + 8*g];
  #pragma unroll
  for (int m = 0; m < 6; m++){
    short8 a0 = *(const short8*)&Als[(16*m + c)*QP +  0 + 8*g];
    short8 a1 = *(const short8*)&Als[(16*m + c)*QP + 32 + 8*g];
    short8 a2 = *(const short8*)&Als[(16*m + c)*QP + 64 + 8*g];
    acc[m] = __builtin_amdgcn_mfma_f32_16x16x32_bf16(a0, b0, acc[m], 0, 0, 0);
    acc[m] = __builtin_amdgcn_mfma_f32_16x16x32_bf16(a1, b1, acc[m], 0, 0, 0);
    acc[m] = __builtin_amdgcn_mfma_f32_16x16x32_bf16(a2, b2, acc[m], 0, 0, 0);
  }

  float2* orow = out + (size_t)blockIdx.y*MM;
  int k1 = blockIdx.x*64 + 16*w + c;
  if (k1 < N2){
    #pragma unroll
    for (int m = 0; m < 6; m++){
      int R0 = 16*m + 4*g;          // even
      int k2a = R0 >> 1;
      int k2b = k2a + 1;
      if (k2a < 41) orow[(size_t)k2a*N2 + k1] = make_float2(acc[m][0], acc[m][1]);
      if (k2b < 41) orow[(size_t)k2b*N2 + k1] = make_float2(acc[m][2], acc[m][3]);
    }
  }
}

extern "C" void kernel_launch(void* const* d_in, const int* in_sizes, int n_in,
                              void* d_out, int out_size, void* d_ws, size_t ws_size,
                              hipStream_t stream){
  const float* s   = (const float*)d_in[0];
  const int*   idx = (const int*)d_in[1];
  const float* gw  = (const float*)d_in[2];
  float2* out = (float2*)d_out;
  char* ws = (char*)d_ws;

  const size_t FWD_BYTES = 21168128;            // >= BATCH*LS*8, 256-aligned
  float2* bufA = (float2*)ws;
  float2* bufB = (float2*)(ws + FWD_BYTES);
  int2*   span = (int2*)(ws + 2*FWD_BYTES);
  unsigned short* A96 = (unsigned short*)(ws + 2*FWD_BYTES + 1024);
  const size_t A_BYTES = 20480;                 // >= 96*QP*2
  unsigned short* Bbase = (unsigned short*)(ws + 2*FWD_BYTES + 1024 + A_BYTES);

  // 0) W-matrix precompute (tiny; L2-resident afterwards)
  a_prep<<<(96*QP + 255)/256, 256, 0, stream>>>(A96);

  // 1) forward FFT: radix-8 r2c + 8 Stockham passes 7,7,5,5,5,3,3,3
  {
    long long tot = (long long)(LS/8)*BATCH;
    int blks = (int)((tot + 255)/256);
    fft_r2c8<<<blks,256,0,stream>>>(s, bufA);
  }
  float2* cur = bufA; float2* nxt = bufB;
  int Ns = 8;
  #define FWD(R) do{                                                         \
    long long tot = (long long)(LS/(R))*BATCH;                               \
    int blks = (int)((tot + 255)/256);                                       \
    fft_pass<R,-1><<<blks,256,0,stream>>>(cur, nxt, LS, Ns, BATCH);          \
    Ns *= (R);                                                               \
    { float2* tmp=cur; cur=nxt; nxt=tmp; }                                   \
  }while(0)
  FWD(7); FWD(7); FWD(5); FWD(5); FWD(5); FWD(3); FWD(3); FWD(3);
  #undef FWD
  // 8 swaps -> ft back in bufA == cur

  // 2) per-row nonzero spans of gw
  rowspan_kernel<<<NB,256,0,stream>>>(gw, span);

  // 3) inverse four-step, chunked by workspace
  const size_t row_bytes = (size_t)SROW * 2;    // 577536 B
  size_t used = 2*FWD_BYTES + 1024 + A_BYTES;
  size_t avail = (ws_size > used) ? (ws_size - used) : 0;
  int max_chunk = (int)(avail / row_bytes);
  if (max_chunk > NROWS_T) max_chunk = NROWS_T;
  if (max_chunk < 1) max_chunk = 1;

  for (int c0 = 0; c0 < NROWS_T; c0 += max_chunk){
    int cr = NROWS_T - c0; if (cr > max_chunk) cr = max_chunk;
    dim3 g1(41, cr);
    inv_s1<<<g1,256,0,stream>>>(cur, idx, gw, span, Bbase, c0);
    dim3 g2(47, cr);   // 47 * 64 = 3008 >= 3000 k1
    inv_s2_mfma<<<g2,256,0,stream>>>(A96, Bbase, out + (size_t)c0*MM);
  }
}

// Round 5
// 528.320 us; speedup vs baseline: 2.0337x; 1.3546x over previous
//
#include <hip/hip_runtime.h>

#define LS 1323000
#define NB 98
#define MM 123000
#define N2 3000            // MM / 41
#define BATCH 2
#define NROWS_T (NB*BATCH)
#define TWO_PI 6.28318530717958647692f

// Bb bf16 layout per row: [kb<188][q<96][kl<16], ushort units
#define KBN 188
#define QN  96
#define SROW (KBN*QN*16)       // 288768 ushorts = 577536 B per row
#define QP  104                // padded q stride in LDS (bank-conflict-free)

typedef __attribute__((ext_vector_type(8))) short short8;
typedef __attribute__((ext_vector_type(4))) float f32x4;

__device__ __forceinline__ float2 cmul(float2 a, float2 b){
  return make_float2(a.x*b.x - a.y*b.y, a.x*b.y + a.y*b.x);
}
__device__ __forceinline__ unsigned short f2bf(float f){
  unsigned int u = __float_as_uint(f);
  unsigned int r = (u + 0x7FFFu + ((u >> 16) & 1u)) >> 16;
  return (unsigned short)r;
}

// Small DFT of size R with sign S (+1 inverse, -1 forward), in-place on v[R].
template<int R,int S>
__device__ __forceinline__ void butterfly(float2* v){
  if constexpr (R==2){
    float2 a=v[0], b=v[1];
    v[0]=make_float2(a.x+b.x, a.y+b.y);
    v[1]=make_float2(a.x-b.x, a.y-b.y);
  } else if constexpr (R==4){
    float2 t0=make_float2(v[0].x+v[2].x, v[0].y+v[2].y);
    float2 t1=make_float2(v[0].x-v[2].x, v[0].y-v[2].y);
    float2 t2=make_float2(v[1].x+v[3].x, v[1].y+v[3].y);
    float2 t3=make_float2(v[1].x-v[3].x, v[1].y-v[3].y);
    v[0]=make_float2(t0.x+t2.x, t0.y+t2.y);
    v[2]=make_float2(t0.x-t2.x, t0.y-t2.y);
    v[1]=make_float2(t1.x - (float)S*t3.y, t1.y + (float)S*t3.x);
    v[3]=make_float2(t1.x + (float)S*t3.y, t1.y - (float)S*t3.x);
  } else if constexpr (R==8){
    float2 e[4]={v[0],v[2],v[4],v[6]};
    float2 o[4]={v[1],v[3],v[5],v[7]};
    butterfly<4,S>(e);
    butterfly<4,S>(o);
    const float h = 0.70710678118654752440f;
    float2 w1=make_float2(h, (float)S*h);
    float2 w2=make_float2(0.f, (float)S);
    float2 w3=make_float2(-h, (float)S*h);
    float2 o1=cmul(o[1],w1), o2=cmul(o[2],w2), o3=cmul(o[3],w3);
    v[0]=make_float2(e[0].x+o[0].x, e[0].y+o[0].y);
    v[4]=make_float2(e[0].x-o[0].x, e[0].y-o[0].y);
    v[1]=make_float2(e[1].x+o1.x, e[1].y+o1.y);
    v[5]=make_float2(e[1].x-o1.x, e[1].y-o1.y);
    v[2]=make_float2(e[2].x+o2.x, e[2].y+o2.y);
    v[6]=make_float2(e[2].x-o2.x, e[2].y-o2.y);
    v[3]=make_float2(e[3].x+o3.x, e[3].y+o3.y);
    v[7]=make_float2(e[3].x-o3.x, e[3].y-o3.y);
  } else {
    float2 x[R];
    #pragma unroll
    for(int k=0;k<R;k++){
      float2 acc=v[0];
      #pragma unroll
      for(int n=1;n<R;n++){
        const int p=(k*n)%R;
        float ang = (float)S * (TWO_PI/(float)R) * (float)p;
        float sn,cs; __sincosf(ang,&sn,&cs);
        acc.x += v[n].x*cs - v[n].y*sn;
        acc.y += v[n].x*sn + v[n].y*cs;
      }
      x[k]=acc;
    }
    #pragma unroll
    for(int k=0;k<R;k++) v[k]=x[k];
  }
}

// One global Stockham pass (forward only).
template<int R,int S>
__global__ void __launch_bounds__(256)
fft_pass(const float2* __restrict__ in, float2* __restrict__ out,
         int N, int Ns, int nrows){
  const int T = N / R;
  long long gid = (long long)blockIdx.x*blockDim.x + threadIdx.x;
  if (gid >= (long long)T*nrows) return;
  int row = (int)(gid / T);
  int j   = (int)(gid - (long long)row*T);
  const float2* x = in  + (size_t)row*N;
  float2*       y = out + (size_t)row*N;
  int t = j % Ns;
  float u = (float)t / (float)(Ns*R);
  float ang = (float)S * TWO_PI * u;
  float sn,cs; __sincosf(ang,&sn,&cs);
  float2 w1=make_float2(cs,sn);
  float2 wr=make_float2(1.f,0.f);
  float2 v[R];
  #pragma unroll
  for(int r=0;r<R;r++){
    float2 a = x[j + r*T];
    v[r] = cmul(a, wr);
    wr = cmul(wr, w1);
  }
  butterfly<R,S>(v);
  int d = (j/Ns)*(Ns*R) + t;
  #pragma unroll
  for(int r=0;r<R;r++) y[d + r*Ns] = v[r];
}

// First forward pass: radix-8, Ns=1 (no twiddles), reads real input directly.
__global__ void __launch_bounds__(256)
fft_r2c8(const float* __restrict__ s, float2* __restrict__ y){
  const int T = LS/8;
  long long gid = (long long)blockIdx.x*blockDim.x + threadIdx.x;
  if (gid >= (long long)T*BATCH) return;
  int row = (int)(gid / T);
  int j   = (int)(gid - (long long)row*T);
  const float* x = s + (size_t)row*LS;
  float2*      yr = y + (size_t)row*LS;
  float2 v[8];
  #pragma unroll
  for(int r=0;r<8;r++) v[r] = make_float2(x[j + r*T], 0.f);
  butterfly<8,-1>(v);
  int d = 8*j;
  #pragma unroll
  for(int r=0;r<8;r++) yr[d + r] = v[r];
}

// ---- parallel rowspan: head-max / tail-min of nonzero gw per row ----
__global__ void span_init(int* __restrict__ spanA, int* __restrict__ spanB){
  int j = blockIdx.x*blockDim.x + threadIdx.x;
  if (j < NB){ spanA[j] = 0; spanB[j] = MM; }
}

#define SPAN_SLICE 4096
__global__ void __launch_bounds__(256)
rowspan_par(const float* __restrict__ gw, int* __restrict__ spanA,
            int* __restrict__ spanB){
  const int j  = blockIdx.x;
  const int lo = blockIdx.y * SPAN_SLICE;
  const int end = min(lo + SPAN_SLICE, MM);
  const float* g = gw + (size_t)j*MM;
  const int tid = threadIdx.x;
  int mA = -1, mB = MM;
  for (int m = lo + tid*4; m < end; m += 256*4){
    float4 v = *(const float4*)(g + m);
    #pragma unroll
    for (int t = 0; t < 4; t++){
      float f = ((const float*)&v)[t];
      int m2 = m + t;
      if (f != 0.f){
        if (m2 < 61500){ if (m2 > mA) mA = m2; }
        else           { if (m2 < mB) mB = m2; }
      }
    }
  }
  __shared__ int sA[256], sB[256];
  sA[tid]=mA; sB[tid]=mB; __syncthreads();
  for (int s=128; s>0; s>>=1){
    if (tid<s){ sA[tid]=max(sA[tid],sA[tid+s]); sB[tid]=min(sB[tid],sB[tid+s]); }
    __syncthreads();
  }
  if (tid==0){
    if (sA[0] >= 0) atomicMax(&spanA[j], sA[0]+1);
    if (sB[0] < MM) atomicMin(&spanB[j], sB[0]);
  }
}

// Precompute the 96x96 (padded to [96][QP]) bf16 real-form W matrix:
// A[2k2+c][2n2+c']: c=0: (Wr, -Wi), c=1: (Wi, Wr), W = e^{2pi i n2 k2/41}.
__global__ void __launch_bounds__(256)
a_prep(unsigned short* __restrict__ A96){
  int i = blockIdx.x*blockDim.x + threadIdx.x;
  if (i >= 96*QP) return;
  int R = i / QP, q = i - R*QP;
  float val = 0.f;
  if (R < 82 && q < 82){
    int k2 = R >> 1, c = R & 1, n2 = q >> 1, cp = q & 1;
    int p = (k2*n2) % 41;
    float ang = (float)p * (TWO_PI/41.f);
    float sn, cs; __sincosf(ang, &sn, &cs);
    val = c ? (cp ? cs : sn) : (cp ? -sn : cs);
  }
  A96[i] = f2bf(val);
}

// LDS Stockham stage for the 3000-pt inverse FFT.
template<int R, int Ns>
__device__ __forceinline__ void lds_stage(const float2* src, float2* dst, int tid){
  const int T = N2 / R;
  for (int j = tid; j < T; j += 256){
    int t = j % Ns;
    float2 w1;
    if constexpr (Ns == 1) w1 = make_float2(1.f, 0.f);
    else {
      float ang = TWO_PI * (float)t / (float)(Ns*R);
      float sn, cs; __sincosf(ang, &sn, &cs);
      w1 = make_float2(cs, sn);
    }
    float2 wr = make_float2(1.f, 0.f);
    float2 v[R];
    #pragma unroll
    for (int r = 0; r < R; r++){ v[r] = cmul(src[j + r*T], wr); wr = cmul(wr, w1); }
    butterfly<R,1>(v);
    int d = (j/Ns)*(Ns*R) + t;
    #pragma unroll
    for (int r = 0; r < R; r++) dst[d + r*Ns] = v[r];
  }
}

// Inverse stage 1: per (row, n2): span-pruned gather -> 3000-pt LDS FFT ->
// twiddle -> bf16 store into MFMA-tiled layout [kb][q=2n2+comp][kl].
__global__ void __launch_bounds__(256)
inv_s1(const float2* __restrict__ ft, const int* __restrict__ idx,
       const float* __restrict__ gw, const int* __restrict__ spanA,
       const int* __restrict__ spanB,
       unsigned short* __restrict__ Bb, int row0){
  __shared__ float2 u0[N2];  // 24 KB
  __shared__ float2 u1[N2];  // 24 KB
  const int n2  = blockIdx.x;            // 0..40
  const int row = row0 + blockIdx.y;
  const int jrow = row % NB;
  const int b    = row / NB;
  const int tid = threadIdx.x;
  const int spA = spanA[jrow], spB = spanB[jrow];
  const int n1A = (spA - n2 + 40) / 41;
  const int n1B = (spB - n2 + 40) / 41;
  const int*   idxr = idx + (size_t)jrow*MM;
  const float* gwr  = gw  + (size_t)jrow*MM;
  const float2* ftb = ft  + (size_t)b*LS;
  for (int i = tid; i < N2; i += 256){
    float2 val = make_float2(0.f, 0.f);
    if (i < n1A || i >= n1B){
      int n = n2 + 41*i;
      int id = idxr[n];
      float g = gwr[n] * (1.0f/(float)MM);
      float2 f = ftb[id];
      val = make_float2(f.x*g, f.y*g);
    }
    u0[i] = val;
  }
  __syncthreads();
  lds_stage<5,1>(u0, u1, tid);   __syncthreads();
  lds_stage<5,5>(u1, u0, tid);   __syncthreads();
  lds_stage<5,25>(u0, u1, tid);  __syncthreads();
  lds_stage<3,125>(u1, u0, tid); __syncthreads();
  lds_stage<8,375>(u0, u1, tid); __syncthreads();
  unsigned short* Brow = Bb + (size_t)blockIdx.y*SROW;
  const int qr = 2*n2, qi = 2*n2+1;
  for (int k1 = tid; k1 < N2; k1 += 256){
    float ang = (float)(n2*k1) * (TWO_PI/(float)MM);  // n2*k1 <= 119960, exact fp32
    float sn, cs; __sincosf(ang, &sn, &cs);
    float2 v = cmul(u1[k1], make_float2(cs, sn));
    int kb = k1 >> 4, kl = k1 & 15;
    size_t base = (size_t)kb*(QN*16) + kl;
    Brow[base + qr*16] = f2bf(v.x);
    Brow[base + qi*16] = f2bf(v.y);
  }
}

// Inverse stage 2 via MFMA: Out[R][k1] = sum_q A96[R][q] * B[q][k1], bf16 in,
// fp32 out. Per block: 64 k1, all 96 R. 4 waves x (6 M-tiles x 3 K-steps).
__global__ void __launch_bounds__(256)
inv_s2_mfma(const unsigned short* __restrict__ A96,
            const unsigned short* __restrict__ Bb,
            float2* __restrict__ out){
  __shared__ unsigned short Als[96*QP];   // 19968 B
  __shared__ unsigned short Bls[64*QP];   // 13312 B
  const int tid = threadIdx.x;

  // stage A (straight copy; hot in L2)
  {
    const uint4* src = (const uint4*)A96;
    uint4* dst = (uint4*)Als;
    for (int f = tid; f < (96*QP*2)/16; f += 256) dst[f] = src[f];
  }
  // stage B tile [4 kb][96 q][16 kl] -> LDS transposed [k1l][q]
  {
    const unsigned short* Bt = Bb + (size_t)blockIdx.y*SROW
                                  + (size_t)blockIdx.x*4*(QN*16);
    for (int f = tid; f < 768; f += 256){
      uint4 d = *(const uint4*)(Bt + (size_t)f*8);
      int q   = (f >> 1) % QN;
      int kb  = f / (QN*2);
      int kl0 = (f & 1) * 8;
      if (q >= 82) d = make_uint4(0u,0u,0u,0u);
      const unsigned short* e = (const unsigned short*)&d;
      int rbase = kb*16 + kl0;
      #pragma unroll
      for (int j = 0; j < 8; j++)
        Bls[(rbase + j)*QP + q] = e[j];
    }
  }
  __syncthreads();

  const int w = tid >> 6, l = tid & 63;
  const int g = l >> 4, c = l & 15;

  f32x4 acc[6];
  #pragma unroll
  for (int m = 0; m < 6; m++) acc[m] = (f32x4){0.f,0.f,0.f,0.f};

  short8 b0 = *(const short8*)&Bls[(16*w + c)*QP +  0 + 8*g];
  short8 b1 = *(const short8*)&Bls[(16*w + c)*QP + 32 + 8*g];
  short8 b2 = *(const short8*)&Bls[(16*w + c)*QP + 64 + 8*g];
  #pragma unroll
  for (int m = 0; m < 6; m++){
    short8 a0 = *(const short8*)&Als[(16*m + c)*QP +  0 + 8*g];
    short8 a1 = *(const short8*)&Als[(16*m + c)*QP + 32 + 8*g];
    short8 a2 = *(const short8*)&Als[(16*m + c)*QP + 64 + 8*g];
    acc[m] = __builtin_amdgcn_mfma_f32_16x16x32_bf16(a0, b0, acc[m], 0, 0, 0);
    acc[m] = __builtin_amdgcn_mfma_f32_16x16x32_bf16(a1, b1, acc[m], 0, 0, 0);
    acc[m] = __builtin_amdgcn_mfma_f32_16x16x32_bf16(a2, b2, acc[m], 0, 0, 0);
  }

  float2* orow = out + (size_t)blockIdx.y*MM;
  int k1 = blockIdx.x*64 + 16*w + c;
  if (k1 < N2){
    #pragma unroll
    for (int m = 0; m < 6; m++){
      int R0 = 16*m + 4*g;          // even
      int k2a = R0 >> 1;
      int k2b = k2a + 1;
      if (k2a < 41) orow[(size_t)k2a*N2 + k1] = make_float2(acc[m][0], acc[m][1]);
      if (k2b < 41) orow[(size_t)k2b*N2 + k1] = make_float2(acc[m][2], acc[m][3]);
    }
  }
}

extern "C" void kernel_launch(void* const* d_in, const int* in_sizes, int n_in,
                              void* d_out, int out_size, void* d_ws, size_t ws_size,
                              hipStream_t stream){
  const float* s   = (const float*)d_in[0];
  const int*   idx = (const int*)d_in[1];
  const float* gw  = (const float*)d_in[2];
  float2* out = (float2*)d_out;
  char* ws = (char*)d_ws;

  const size_t FWD_BYTES = 21168128;            // >= BATCH*LS*8, 256-aligned
  float2* bufA = (float2*)ws;
  float2* bufB = (float2*)(ws + FWD_BYTES);
  int* spanA = (int*)(ws + 2*FWD_BYTES);
  int* spanB = (int*)(ws + 2*FWD_BYTES + 512);
  unsigned short* A96 = (unsigned short*)(ws + 2*FWD_BYTES + 1024);
  const size_t A_BYTES = 20480;                 // >= 96*QP*2
  unsigned short* Bbase = (unsigned short*)(ws + 2*FWD_BYTES + 1024 + A_BYTES);

  // 0) W-matrix precompute + span init + parallel span scan (~48 MB, BW-bound)
  a_prep<<<(96*QP + 255)/256, 256, 0, stream>>>(A96);
  span_init<<<1, 128, 0, stream>>>(spanA, spanB);
  {
    dim3 g(NB, (MM + SPAN_SLICE - 1)/SPAN_SLICE);   // (98, 31)
    rowspan_par<<<g, 256, 0, stream>>>(gw, spanA, spanB);
  }

  // 1) forward FFT: radix-8 r2c + 8 Stockham passes 7,7,5,5,5,3,3,3
  {
    long long tot = (long long)(LS/8)*BATCH;
    int blks = (int)((tot + 255)/256);
    fft_r2c8<<<blks,256,0,stream>>>(s, bufA);
  }
  float2* cur = bufA; float2* nxt = bufB;
  int Ns = 8;
  #define FWD(R) do{                                                         \
    long long tot = (long long)(LS/(R))*BATCH;                               \
    int blks = (int)((tot + 255)/256);                                       \
    fft_pass<R,-1><<<blks,256,0,stream>>>(cur, nxt, LS, Ns, BATCH);          \
    Ns *= (R);                                                               \
    { float2* tmp=cur; cur=nxt; nxt=tmp; }                                   \
  }while(0)
  FWD(7); FWD(7); FWD(5); FWD(5); FWD(5); FWD(3); FWD(3); FWD(3);
  #undef FWD
  // 8 swaps -> ft back in bufA == cur

  // 2) inverse four-step, chunked by workspace
  const size_t row_bytes = (size_t)SROW * 2;    // 577536 B
  size_t used = 2*FWD_BYTES + 1024 + A_BYTES;
  size_t avail = (ws_size > used) ? (ws_size - used) : 0;
  int max_chunk = (int)(avail / row_bytes);
  if (max_chunk > NROWS_T) max_chunk = NROWS_T;
  if (max_chunk < 1) max_chunk = 1;

  for (int c0 = 0; c0 < NROWS_T; c0 += max_chunk){
    int cr = NROWS_T - c0; if (cr > max_chunk) cr = max_chunk;
    dim3 g1(41, cr);
    inv_s1<<<g1,256,0,stream>>>(cur, idx, gw, spanA, spanB, Bbase, c0);
    dim3 g2(47, cr);   // 47 * 64 = 3008 >= 3000 k1
    inv_s2_mfma<<<g2,256,0,stream>>>(A96, Bbase, out + (size_t)c0*MM);
  }
}